// Round 3
// baseline (51.617 us; speedup 1.0000x reference)
//
#include <hip/hip_runtime.h>

// Problem constants (match reference)
#define HX 32
#define HY 32
#define UU 64
#define VV 64
#define LL 16
#define NQ 524288

typedef float f32x4 __attribute__((ext_vector_type(4)));  // native vec type

// latents: [HX][HY][UU][VV][LL] float32. 64B per (hx,hy,u,v) cell vector.
// u,v indices are integers after floor -> quadrilinear degenerates to
// bilinear over (hx,hy) at fixed (k1,l1): 4 corner gathers of 64B each.
// 4 lanes per query, each owning one float4 quarter -> each corner gather
// is one 64B line covered by 4 consecutive lanes.
// 2 queries per thread -> 8 independent gathers in flight.

__global__ __launch_bounds__(256) void latents_interp_kernel(
    const float* __restrict__ latents,
    const float2* __restrict__ h,
    const float* __restrict__ u,
    const float* __restrict__ v,
    float* __restrict__ out)
{
    const int tid = blockIdx.x * blockDim.x + threadIdx.x;
    const int g = tid >> 2;       // 0 .. NQ/2-1
    const int q = tid & 3;        // float4 quarter
    if (g >= (NQ / 2)) return;

    const int n0 = g;
    const int n1 = g + (NQ / 2);

    // ---- index math for both queries ----
    const float2 hh0 = h[n0];
    const float2 hh1 = h[n1];
    const float uu0 = u[n0], uu1 = u[n1];
    const float vv0 = v[n0], vv1 = v[n1];

    float ix0 = (hh0.x + 1.0f) * 0.5f * (float)HX;
    float iy0 = (hh0.y + 1.0f) * 0.5f * (float)HY;
    float ix1 = (hh1.x + 1.0f) * 0.5f * (float)HX;
    float iy1 = (hh1.y + 1.0f) * 0.5f * (float)HY;
    if (ix0 >= (float)HX) ix0 = (float)HX - 1.0f;
    if (iy0 >= (float)HY) iy0 = (float)HY - 1.0f;
    if (ix1 >= (float)HX) ix1 = (float)HX - 1.0f;
    if (iy1 >= (float)HY) iy1 = (float)HY - 1.0f;
    float fu0 = uu0 * (float)UU; if (fu0 >= (float)UU) fu0 = (float)UU - 1.0f;
    float fv0 = vv0 * (float)VV; if (fv0 >= (float)VV) fv0 = (float)VV - 1.0f;
    float fu1 = uu1 * (float)UU; if (fu1 >= (float)UU) fu1 = (float)UU - 1.0f;
    float fv1 = vv1 * (float)VV; if (fv1 >= (float)VV) fv1 = (float)VV - 1.0f;

    const int i1_0 = (int)floorf(ix0), j1_0 = (int)floorf(iy0);
    const int i1_1 = (int)floorf(ix1), j1_1 = (int)floorf(iy1);
    const int k1_0 = (int)floorf(fu0), l1_0 = (int)floorf(fv0);
    const int k1_1 = (int)floorf(fu1), l1_1 = (int)floorf(fv1);
    const float ir0 = ix0 - (float)i1_0, jr0 = iy0 - (float)j1_0;
    const float ir1 = ix1 - (float)i1_1, jr1 = iy1 - (float)j1_1;
    const int i2_0 = (i1_0 + 1) & (HX - 1), j2_0 = (j1_0 + 1) & (HY - 1);
    const int i2_1 = (i1_1 + 1) & (HX - 1), j2_1 = (j1_1 + 1) & (HY - 1);

    // float4-unit strides
    const int s_i4 = (HY * UU * VV * LL) >> 2;  // 524288
    const int s_j4 = (UU * VV * LL) >> 2;       // 16384
    const int c4_0 = (k1_0 * VV + l1_0) * (LL >> 2) + q;
    const int c4_1 = (k1_1 * VV + l1_1) * (LL >> 2) + q;

    const f32x4* __restrict__ lat4 = (const f32x4*)latents;

    // ---- issue all 8 gathers (independent; stay in flight together) ----
    const f32x4 a00 = lat4[i1_0 * s_i4 + j1_0 * s_j4 + c4_0];
    const f32x4 a01 = lat4[i1_0 * s_i4 + j2_0 * s_j4 + c4_0];
    const f32x4 a10 = lat4[i2_0 * s_i4 + j1_0 * s_j4 + c4_0];
    const f32x4 a11 = lat4[i2_0 * s_i4 + j2_0 * s_j4 + c4_0];
    const f32x4 b00 = lat4[i1_1 * s_i4 + j1_1 * s_j4 + c4_1];
    const f32x4 b01 = lat4[i1_1 * s_i4 + j2_1 * s_j4 + c4_1];
    const f32x4 b10 = lat4[i2_1 * s_i4 + j1_1 * s_j4 + c4_1];
    const f32x4 b11 = lat4[i2_1 * s_i4 + j2_1 * s_j4 + c4_1];

    // ---- lerps, replicate reference ordering:
    // res = (m00*(1-jr) + m01*jr)*(1-ir) + (m10*(1-jr) + m11*jr)*ir
    const float wj0a = 1.0f - jr0, wi0a = 1.0f - ir0;
    const float wj0b = 1.0f - jr1, wi0b = 1.0f - ir1;

    const f32x4 r0 = (a00 * wj0a + a01 * jr0) * wi0a + (a10 * wj0a + a11 * jr0) * ir0;
    const f32x4 r1 = (b00 * wj0b + b01 * jr1) * wi0b + (b10 * wj0b + b11 * jr1) * ir1;

    f32x4* out4 = (f32x4*)out;
    // nontemporal: out has zero reuse; keep L2/L3 capacity for latents
    __builtin_nontemporal_store(r0, &out4[n0 * 4 + q]);
    __builtin_nontemporal_store(r1, &out4[n1 * 4 + q]);
}

extern "C" void kernel_launch(void* const* d_in, const int* in_sizes, int n_in,
                              void* d_out, int out_size, void* d_ws, size_t ws_size,
                              hipStream_t stream) {
    // setup_inputs order: latents, r(unused), h, u, v, radius(=0 -> blur identity)
    const float*  latents = (const float*)d_in[0];
    const float2* h       = (const float2*)d_in[2];
    const float*  u       = (const float*)d_in[3];
    const float*  v       = (const float*)d_in[4];
    float* out = (float*)d_out;

    const int total = (NQ / 2) * 4;           // 2 queries per thread, 4 lanes/query
    const int block = 256;
    const int grid = (total + block - 1) / block;  // 4096
    latents_interp_kernel<<<grid, block, 0, stream>>>(latents, h, u, v, out);
}